// Round 5
// baseline (802.022 us; speedup 1.0000x reference)
//
#include <hip/hip_runtime.h>
#include <hip/hip_bf16.h>
#include <math.h>

#define N_NODES 50000
#define N_EDGES 800000
#define D 64
#define ED 32

// ws layout (float-slot offsets)
#define Q_OFF    0          // bf16 q: 3.2M bf16 = 1.6M slots
#define K_OFF    1600000    // bf16 k
#define V_OFF    3200000    // bf16 v
#define OS_OFF   4800000    // f32 out_sum 3.2M
#define CNT_OFF  8000000    // 50,000
#define S_OFF    8050000    // 16
#define MSG_OFF  8050016    // bf16 msgs: 800k*64 = 51.2M bf16 = 25.6M slots
#define EID_OFF  33650016   // 800k ints
#define DEG_OFF  34450016   // 50k ints
#define RP_OFF   34500016   // 50,001 ints
#define WOFF_OFF 34550018   // 50k ints
#define BSUM_OFF 34600018   // 256 ints
// total ~34.6M floats ~ 138 MB
#define H_OFF    0          // h f32 3.2M aliases q/k/v (dead after gather)
#define F1_OFF   MSG_OFF    // f1 f32 6.4M aliases msg (dead after gather)

__device__ __forceinline__ ushort f2bf(float f) {
  uint u = __float_as_uint(f);
  uint r = (u + 0x7FFFu + ((u >> 16) & 1u)) >> 16;
  return (ushort)r;
}
__device__ __forceinline__ float bf2f(ushort u) {
  return __uint_as_float(((uint)u) << 16);
}

// ---------------- node QKV projection -> bf16, thread per node, W in LDS ----------------
__global__ __launch_bounds__(256) void k_qkv(
    const float* __restrict__ x,
    const float* __restrict__ Wq, const float* __restrict__ bq,
    const float* __restrict__ Wk, const float* __restrict__ bk,
    const float* __restrict__ Wv, const float* __restrict__ bv,
    ushort* __restrict__ q, ushort* __restrict__ k, ushort* __restrict__ v) {
  __shared__ float Wl[64 * 64];
  const float* W; const float* b; ushort* o;
  if (blockIdx.y == 0)      { W = Wq; b = bq; o = q; }
  else if (blockIdx.y == 1) { W = Wk; b = bk; o = k; }
  else                      { W = Wv; b = bv; o = v; }
  for (int t = threadIdx.x; t < 4096; t += 256) Wl[t] = W[t];
  __syncthreads();
  const int n = blockIdx.x * 256 + threadIdx.x;
  if (n >= N_NODES) return;

  float4 acc[16];
#pragma unroll
  for (int j4 = 0; j4 < 16; ++j4) acc[j4] = make_float4(0.f, 0.f, 0.f, 0.f);
  const float4* xr = reinterpret_cast<const float4*>(x + (size_t)n * 64);
#pragma unroll 2
  for (int i4 = 0; i4 < 16; ++i4) {
    float4 xv = xr[i4];
#pragma unroll
    for (int s = 0; s < 4; ++s) {
      const float xi = (s == 0) ? xv.x : (s == 1) ? xv.y : (s == 2) ? xv.z : xv.w;
      const float4* wrow = reinterpret_cast<const float4*>(Wl + (i4 * 4 + s) * 64);
#pragma unroll
      for (int j4 = 0; j4 < 16; ++j4) {
        float4 wv = wrow[j4];
        acc[j4].x = fmaf(xi, wv.x, acc[j4].x);
        acc[j4].y = fmaf(xi, wv.y, acc[j4].y);
        acc[j4].z = fmaf(xi, wv.z, acc[j4].z);
        acc[j4].w = fmaf(xi, wv.w, acc[j4].w);
      }
    }
  }
  const float4* b4 = reinterpret_cast<const float4*>(b);
  uint2* orow = reinterpret_cast<uint2*>(o + (size_t)n * 64);
#pragma unroll
  for (int j4 = 0; j4 < 16; ++j4) {
    float4 a = acc[j4]; float4 bb = b4[j4];
    a.x += bb.x; a.y += bb.y; a.z += bb.z; a.w += bb.w;
    uint2 pk;
    pk.x = (uint)f2bf(a.x) | ((uint)f2bf(a.y) << 16);
    pk.y = (uint)f2bf(a.z) | ((uint)f2bf(a.w) << 16);
    orow[j4] = pk;
  }
}

// ---------------- CSR build: histogram ----------------
__global__ __launch_bounds__(256) void k_hist(const int* __restrict__ edst,
                                              int* __restrict__ deg) {
  const int i = blockIdx.x * 256 + threadIdx.x;
  if (i < N_EDGES) atomicAdd(&deg[edst[i]], 1);
}

// ---------------- CSR build: 3-stage multi-block scan ----------------
__global__ __launch_bounds__(256) void k_scan_a(const int* __restrict__ deg,
                                                int* __restrict__ bsum) {
  __shared__ int lds[256];
  const int i = blockIdx.x * 256 + threadIdx.x;
  lds[threadIdx.x] = (i < N_NODES) ? deg[i] : 0;
  __syncthreads();
  for (int s = 128; s > 0; s >>= 1) {
    if (threadIdx.x < s) lds[threadIdx.x] += lds[threadIdx.x + s];
    __syncthreads();
  }
  if (threadIdx.x == 0) bsum[blockIdx.x] = lds[0];
}

__global__ __launch_bounds__(256) void k_scan_b(int* __restrict__ bsum, int nb) {
  __shared__ int lds[256];
  const int t = threadIdx.x;
  const int d = (t < nb) ? bsum[t] : 0;
  lds[t] = d;
  __syncthreads();
  for (int off = 1; off < 256; off <<= 1) {
    const int val = (t >= off) ? lds[t - off] : 0;
    __syncthreads();
    lds[t] += val;
    __syncthreads();
  }
  if (t < nb) bsum[t] = lds[t] - d;  // exclusive
}

__global__ __launch_bounds__(256) void k_scan_c(const int* __restrict__ deg,
                                                const int* __restrict__ bsum,
                                                int* __restrict__ rowptr,
                                                int* __restrict__ woff) {
  __shared__ int lds[256];
  const int i = blockIdx.x * 256 + threadIdx.x;
  const int d = (i < N_NODES) ? deg[i] : 0;
  lds[threadIdx.x] = d;
  __syncthreads();
  for (int off = 1; off < 256; off <<= 1) {
    const int val = (threadIdx.x >= off) ? lds[threadIdx.x - off] : 0;
    __syncthreads();
    lds[threadIdx.x] += val;
    __syncthreads();
  }
  const int ex = bsum[blockIdx.x] + lds[threadIdx.x] - d;
  if (i < N_NODES) { rowptr[i] = ex; woff[i] = ex; }
  if (i == N_NODES - 1) rowptr[N_NODES] = ex + d;
}

// ---------------- CSR build: scatter eid by dst ----------------
__global__ __launch_bounds__(256) void k_scatter(const int* __restrict__ edst,
                                                 int* __restrict__ woff,
                                                 int* __restrict__ eid_perm) {
  const int i = blockIdx.x * 256 + threadIdx.x;
  if (i < N_EDGES) {
    const int d = edst[i];
    const int pos = atomicAdd(&woff[d], 1);
    eid_perm[pos] = i;
  }
}

// ---------------- edge precompute: msg[e] = w*(v[src]+ee), S += w ----------------
// Wave per 64-edge batch, original edge order: ea reads sequential, msg writes
// sequential coalesced. No atomics except the final 8 S-adds per wave.
__global__ __launch_bounds__(256) void k_edge_pre(
    const int* __restrict__ esrc, const int* __restrict__ edst,
    const float* __restrict__ ea,
    const ushort* __restrict__ qb, const ushort* __restrict__ kb,
    const ushort* __restrict__ vb,
    const float* __restrict__ We, const float* __restrict__ be,
    ushort* __restrict__ msg, float* __restrict__ S) {
  const int lane = threadIdx.x & 63;
  const int wid  = threadIdx.x >> 6;
  float wec[32];
#pragma unroll
  for (int i = 0; i < 32; ++i) wec[i] = We[i * 64 + lane];
  const float bel = be[lane];
  float sacc = 0.f;

  const int nbatch = N_EDGES / 64;  // 12500 exact
  const int wstride = gridDim.x * 4;
  for (int b = blockIdx.x * 4 + wid; b < nbatch; b += wstride) {
    const int base = b * 64;
    const int srcv = esrc[base + lane];
    const int dstv = edst[base + lane];
    for (int t = 0; t < 64; ++t) {
      const int s  = __shfl(srcv, t);
      const int d2 = __shfl(dstv, t);
      const float4* er = reinterpret_cast<const float4*>(ea + (size_t)(base + t) * 32);
      const float4 c0 = er[0], c1 = er[1], c2 = er[2], c3 = er[3];
      const float4 c4 = er[4], c5 = er[5], c6 = er[6], c7 = er[7];
      const float kj = bf2f(kb[(size_t)s * 64 + lane]);
      const float vj = bf2f(vb[(size_t)s * 64 + lane]);
      const float qj = bf2f(qb[(size_t)d2 * 64 + lane]);
      float e0 = bel, e1 = 0.f, e2 = 0.f, e3 = 0.f;
      e0 = fmaf(c0.x, wec[0],  e0); e1 = fmaf(c0.y, wec[1],  e1);
      e2 = fmaf(c0.z, wec[2],  e2); e3 = fmaf(c0.w, wec[3],  e3);
      e0 = fmaf(c1.x, wec[4],  e0); e1 = fmaf(c1.y, wec[5],  e1);
      e2 = fmaf(c1.z, wec[6],  e2); e3 = fmaf(c1.w, wec[7],  e3);
      e0 = fmaf(c2.x, wec[8],  e0); e1 = fmaf(c2.y, wec[9],  e1);
      e2 = fmaf(c2.z, wec[10], e2); e3 = fmaf(c2.w, wec[11], e3);
      e0 = fmaf(c3.x, wec[12], e0); e1 = fmaf(c3.y, wec[13], e1);
      e2 = fmaf(c3.z, wec[14], e2); e3 = fmaf(c3.w, wec[15], e3);
      e0 = fmaf(c4.x, wec[16], e0); e1 = fmaf(c4.y, wec[17], e1);
      e2 = fmaf(c4.z, wec[18], e2); e3 = fmaf(c4.w, wec[19], e3);
      e0 = fmaf(c5.x, wec[20], e0); e1 = fmaf(c5.y, wec[21], e1);
      e2 = fmaf(c5.z, wec[22], e2); e3 = fmaf(c5.w, wec[23], e3);
      e0 = fmaf(c6.x, wec[24], e0); e1 = fmaf(c6.y, wec[25], e1);
      e2 = fmaf(c6.z, wec[26], e2); e3 = fmaf(c6.w, wec[27], e3);
      e0 = fmaf(c7.x, wec[28], e0); e1 = fmaf(c7.y, wec[29], e1);
      e2 = fmaf(c7.z, wec[30], e2); e3 = fmaf(c7.w, wec[31], e3);
      const float eej = (e0 + e1) + (e2 + e3);
      float p = qj * (kj + eej);
      p += __shfl_xor(p, 1);
      p += __shfl_xor(p, 2);
      p += __shfl_xor(p, 4);
      const float wv = __expf(p * 0.3535533905932738f);  // 1/sqrt(8)
      if ((lane & 7) == 0) sacc += wv;
      msg[(size_t)(base + t) * 64 + lane] = f2bf(wv * (vj + eej));
    }
  }
  if ((lane & 7) == 0) atomicAdd(&S[lane >> 3], sacc);
}

// ---------------- gather: wave per node, stream msg rows, no atomics ----------------
__global__ __launch_bounds__(256) void k_gather_sum(
    const int* __restrict__ rowptr, const int* __restrict__ eid_perm,
    const ushort* __restrict__ msg,
    const ushort* __restrict__ qb, const ushort* __restrict__ kb,
    const ushort* __restrict__ vb, const float* __restrict__ be,
    float* __restrict__ osum, float* __restrict__ cnt, float* __restrict__ S) {
  const int lane = threadIdx.x & 63;
  const int wid  = threadIdx.x >> 6;
  const float bel = be[lane];
  float sacc = 0.f;
  const int nw = gridDim.x * 4;
  for (int n = blockIdx.x * 4 + wid; n < N_NODES; n += nw) {
    const int beg = rowptr[n];
    const int end = rowptr[n + 1];
    // self-loop: ee = be
    const float qj = bf2f(qb[(size_t)n * 64 + lane]);
    const float kj = bf2f(kb[(size_t)n * 64 + lane]);
    const float vj = bf2f(vb[(size_t)n * 64 + lane]);
    float p = qj * (kj + bel);
    p += __shfl_xor(p, 1);
    p += __shfl_xor(p, 2);
    p += __shfl_xor(p, 4);
    const float wv = __expf(p * 0.3535533905932738f);
    if ((lane & 7) == 0) sacc += wv;
    float macc = wv * (vj + bel);

    for (int jb = beg; jb < end; jb += 64) {
      const int m = (end - jb < 64) ? (end - jb) : 64;
      const int eidv = (jb + lane < end) ? eid_perm[jb + lane] : 0;
      int t = 0;
      for (; t + 4 <= m; t += 4) {
        const int a0 = __shfl(eidv, t);
        const int a1 = __shfl(eidv, t + 1);
        const int a2 = __shfl(eidv, t + 2);
        const int a3 = __shfl(eidv, t + 3);
        const float m0 = bf2f(msg[(size_t)a0 * 64 + lane]);
        const float m1 = bf2f(msg[(size_t)a1 * 64 + lane]);
        const float m2 = bf2f(msg[(size_t)a2 * 64 + lane]);
        const float m3 = bf2f(msg[(size_t)a3 * 64 + lane]);
        macc += (m0 + m1) + (m2 + m3);
      }
      for (; t < m; ++t) {
        const int a0 = __shfl(eidv, t);
        macc += bf2f(msg[(size_t)a0 * 64 + lane]);
      }
    }
    osum[(size_t)n * 64 + lane] = macc;
    if (lane == 0) cnt[n] = (float)(end - beg + 1);
  }
  if ((lane & 7) == 0) atomicAdd(&S[lane >> 3], sacc);
}

// ---------------- epilogue 1: out/(S*cnt) @ Wo + bo, +x, LN1 -> h ----------------
__global__ __launch_bounds__(256) void k_ln1(
    const float* __restrict__ osum, const float* __restrict__ cnt,
    const float* __restrict__ S, const float* __restrict__ x,
    const float* __restrict__ Wo, const float* __restrict__ bo,
    const float* __restrict__ g1, const float* __restrict__ b1,
    float* __restrict__ h) {
  __shared__ float Wl[64 * 64];
  for (int t = threadIdx.x; t < 4096; t += 256) Wl[t] = Wo[t];
  __syncthreads();
  const int n = blockIdx.x * 256 + threadIdx.x;
  if (n >= N_NODES) return;

  float inv[8];
#pragma unroll
  for (int hh = 0; hh < 8; ++hh) inv[hh] = 1.0f / S[hh];
  const float invc = 1.0f / cnt[n];

  float val[64];
  const float4* osr = reinterpret_cast<const float4*>(osum + (size_t)n * 64);
#pragma unroll
  for (int j4 = 0; j4 < 16; ++j4) {
    float4 t = osr[j4];
    val[j4 * 4 + 0] = t.x * inv[(j4 * 4 + 0) >> 3] * invc;
    val[j4 * 4 + 1] = t.y * inv[(j4 * 4 + 1) >> 3] * invc;
    val[j4 * 4 + 2] = t.z * inv[(j4 * 4 + 2) >> 3] * invc;
    val[j4 * 4 + 3] = t.w * inv[(j4 * 4 + 3) >> 3] * invc;
  }

  float4 acc[16];
#pragma unroll
  for (int j4 = 0; j4 < 16; ++j4) acc[j4] = make_float4(0.f, 0.f, 0.f, 0.f);
#pragma unroll 4
  for (int i = 0; i < 64; ++i) {
    const float xi = val[i];
    const float4* wrow = reinterpret_cast<const float4*>(Wl + i * 64);
#pragma unroll
    for (int j4 = 0; j4 < 16; ++j4) {
      float4 wv = wrow[j4];
      acc[j4].x = fmaf(xi, wv.x, acc[j4].x);
      acc[j4].y = fmaf(xi, wv.y, acc[j4].y);
      acc[j4].z = fmaf(xi, wv.z, acc[j4].z);
      acc[j4].w = fmaf(xi, wv.w, acc[j4].w);
    }
  }

  const float4* xr = reinterpret_cast<const float4*>(x + (size_t)n * 64);
  const float4* bo4 = reinterpret_cast<const float4*>(bo);
  float t[64];
  float m = 0.f;
#pragma unroll
  for (int j4 = 0; j4 < 16; ++j4) {
    float4 xv = xr[j4]; float4 bb = bo4[j4];
    t[j4 * 4 + 0] = xv.x + acc[j4].x + bb.x;
    t[j4 * 4 + 1] = xv.y + acc[j4].y + bb.y;
    t[j4 * 4 + 2] = xv.z + acc[j4].z + bb.z;
    t[j4 * 4 + 3] = xv.w + acc[j4].w + bb.w;
    m += t[j4 * 4 + 0] + t[j4 * 4 + 1] + t[j4 * 4 + 2] + t[j4 * 4 + 3];
  }
  m *= (1.0f / 64.0f);
  float var = 0.f;
#pragma unroll
  for (int j = 0; j < 64; ++j) { const float dt = t[j] - m; var = fmaf(dt, dt, var); }
  var *= (1.0f / 64.0f);
  const float r = rsqrtf(var + 1e-5f);
  const float4* g14 = reinterpret_cast<const float4*>(g1);
  const float4* b14 = reinterpret_cast<const float4*>(b1);
  float4* hr = reinterpret_cast<float4*>(h + (size_t)n * 64);
#pragma unroll
  for (int j4 = 0; j4 < 16; ++j4) {
    float4 g = g14[j4]; float4 bb = b14[j4]; float4 o;
    o.x = (t[j4 * 4 + 0] - m) * r * g.x + bb.x;
    o.y = (t[j4 * 4 + 1] - m) * r * g.y + bb.y;
    o.z = (t[j4 * 4 + 2] - m) * r * g.z + bb.z;
    o.w = (t[j4 * 4 + 3] - m) * r * g.w + bb.w;
    hr[j4] = o;
  }
}

// ---------------- FFN stage 1: f1 = gelu(h @ Wf1 + bf1) ----------------
__global__ __launch_bounds__(256) void k_ffn1(
    const float* __restrict__ h, const float* __restrict__ Wf1,
    const float* __restrict__ bf1, float* __restrict__ f1) {
  __shared__ float Wl[64 * 128];
  for (int t = threadIdx.x; t < 8192; t += 256) Wl[t] = Wf1[t];
  __syncthreads();
  const int n = blockIdx.x * 256 + threadIdx.x;
  if (n >= N_NODES) return;

  float4 acc[32];
#pragma unroll
  for (int j4 = 0; j4 < 32; ++j4) acc[j4] = make_float4(0.f, 0.f, 0.f, 0.f);
  const float4* xr = reinterpret_cast<const float4*>(h + (size_t)n * 64);
#pragma unroll 2
  for (int i4 = 0; i4 < 16; ++i4) {
    float4 xv = xr[i4];
#pragma unroll
    for (int s = 0; s < 4; ++s) {
      const float xi = (s == 0) ? xv.x : (s == 1) ? xv.y : (s == 2) ? xv.z : xv.w;
      const float4* wrow = reinterpret_cast<const float4*>(Wl + (i4 * 4 + s) * 128);
#pragma unroll
      for (int j4 = 0; j4 < 32; ++j4) {
        float4 wv = wrow[j4];
        acc[j4].x = fmaf(xi, wv.x, acc[j4].x);
        acc[j4].y = fmaf(xi, wv.y, acc[j4].y);
        acc[j4].z = fmaf(xi, wv.z, acc[j4].z);
        acc[j4].w = fmaf(xi, wv.w, acc[j4].w);
      }
    }
  }
  const float4* b4 = reinterpret_cast<const float4*>(bf1);
  float4* orow = reinterpret_cast<float4*>(f1 + (size_t)n * 128);
#pragma unroll
  for (int j4 = 0; j4 < 32; ++j4) {
    float4 a = acc[j4]; float4 bb = b4[j4];
    a.x += bb.x; a.y += bb.y; a.z += bb.z; a.w += bb.w;
    a.x = 0.5f * a.x * (1.0f + erff(a.x * 0.7071067811865475f));
    a.y = 0.5f * a.y * (1.0f + erff(a.y * 0.7071067811865475f));
    a.z = 0.5f * a.z * (1.0f + erff(a.z * 0.7071067811865475f));
    a.w = 0.5f * a.w * (1.0f + erff(a.w * 0.7071067811865475f));
    orow[j4] = a;
  }
}

// ---------------- FFN stage 2 + residual + LN2 -> d_out ----------------
__global__ __launch_bounds__(256) void k_ffn2(
    const float* __restrict__ f1, const float* __restrict__ h,
    const float* __restrict__ Wf2, const float* __restrict__ bf2,
    const float* __restrict__ g2, const float* __restrict__ b2,
    float* __restrict__ out) {
  __shared__ float Wl[128 * 64];
  for (int t = threadIdx.x; t < 8192; t += 256) Wl[t] = Wf2[t];
  __syncthreads();
  const int n = blockIdx.x * 256 + threadIdx.x;
  if (n >= N_NODES) return;

  float4 acc[16];
#pragma unroll
  for (int j4 = 0; j4 < 16; ++j4) acc[j4] = make_float4(0.f, 0.f, 0.f, 0.f);
  const float4* fr = reinterpret_cast<const float4*>(f1 + (size_t)n * 128);
#pragma unroll 2
  for (int i4 = 0; i4 < 32; ++i4) {
    float4 fv = fr[i4];
#pragma unroll
    for (int s = 0; s < 4; ++s) {
      const float fi = (s == 0) ? fv.x : (s == 1) ? fv.y : (s == 2) ? fv.z : fv.w;
      const float4* wrow = reinterpret_cast<const float4*>(Wl + (i4 * 4 + s) * 64);
#pragma unroll
      for (int j4 = 0; j4 < 16; ++j4) {
        float4 wv = wrow[j4];
        acc[j4].x = fmaf(fi, wv.x, acc[j4].x);
        acc[j4].y = fmaf(fi, wv.y, acc[j4].y);
        acc[j4].z = fmaf(fi, wv.z, acc[j4].z);
        acc[j4].w = fmaf(fi, wv.w, acc[j4].w);
      }
    }
  }

  const float4* hr = reinterpret_cast<const float4*>(h + (size_t)n * 64);
  const float4* b4 = reinterpret_cast<const float4*>(bf2);
  float t[64];
  float m = 0.f;
#pragma unroll
  for (int j4 = 0; j4 < 16; ++j4) {
    float4 hv = hr[j4]; float4 bb = b4[j4];
    t[j4 * 4 + 0] = hv.x + acc[j4].x + bb.x;
    t[j4 * 4 + 1] = hv.y + acc[j4].y + bb.y;
    t[j4 * 4 + 2] = hv.z + acc[j4].z + bb.z;
    t[j4 * 4 + 3] = hv.w + acc[j4].w + bb.w;
    m += t[j4 * 4 + 0] + t[j4 * 4 + 1] + t[j4 * 4 + 2] + t[j4 * 4 + 3];
  }
  m *= (1.0f / 64.0f);
  float var = 0.f;
#pragma unroll
  for (int j = 0; j < 64; ++j) { const float dt = t[j] - m; var = fmaf(dt, dt, var); }
  var *= (1.0f / 64.0f);
  const float r = rsqrtf(var + 1e-5f);
  const float4* g24 = reinterpret_cast<const float4*>(g2);
  const float4* b24 = reinterpret_cast<const float4*>(b2);
  float4* orow = reinterpret_cast<float4*>(out + (size_t)n * 64);
#pragma unroll
  for (int j4 = 0; j4 < 16; ++j4) {
    float4 g = g24[j4]; float4 bb = b24[j4]; float4 o;
    o.x = (t[j4 * 4 + 0] - m) * r * g.x + bb.x;
    o.y = (t[j4 * 4 + 1] - m) * r * g.y + bb.y;
    o.z = (t[j4 * 4 + 2] - m) * r * g.z + bb.z;
    o.w = (t[j4 * 4 + 3] - m) * r * g.w + bb.w;
    orow[j4] = o;
  }
}

extern "C" void kernel_launch(void* const* d_in, const int* in_sizes, int n_in,
                              void* d_out, int out_size, void* d_ws, size_t ws_size,
                              hipStream_t stream) {
  const float* x    = (const float*)d_in[0];
  const int*   ei   = (const int*)d_in[1];
  const int*   esrc = ei;
  const int*   edst = ei + N_EDGES;
  const float* ea   = (const float*)d_in[2];
  const float* Wq   = (const float*)d_in[3];
  const float* bq   = (const float*)d_in[4];
  const float* Wk   = (const float*)d_in[5];
  const float* bk   = (const float*)d_in[6];
  const float* Wv   = (const float*)d_in[7];
  const float* bv   = (const float*)d_in[8];
  const float* We   = (const float*)d_in[9];
  const float* be   = (const float*)d_in[10];
  const float* Wo   = (const float*)d_in[11];
  const float* bo   = (const float*)d_in[12];
  const float* g1   = (const float*)d_in[13];
  const float* b1   = (const float*)d_in[14];
  const float* g2   = (const float*)d_in[15];
  const float* b2   = (const float*)d_in[16];
  const float* Wf1  = (const float*)d_in[17];
  const float* bf1  = (const float*)d_in[18];
  const float* Wf2  = (const float*)d_in[19];
  const float* bf2  = (const float*)d_in[20];

  float* ws   = (float*)d_ws;
  ushort* q   = (ushort*)(ws + Q_OFF);
  ushort* k   = (ushort*)(ws + K_OFF);
  ushort* v   = (ushort*)(ws + V_OFF);
  float* osum = ws + OS_OFF;
  float* cnt  = ws + CNT_OFF;
  float* S    = ws + S_OFF;
  ushort* msg = (ushort*)(ws + MSG_OFF);
  int*   eidp = (int*)(ws + EID_OFF);
  int*   deg    = (int*)(ws + DEG_OFF);
  int*   rowptr = (int*)(ws + RP_OFF);
  int*   woff   = (int*)(ws + WOFF_OFF);
  int*   bsum   = (int*)(ws + BSUM_OFF);
  float* h    = ws + H_OFF;
  float* f1   = ws + F1_OFF;
  float* out  = (float*)d_out;

  hipMemsetAsync(deg, 0, (size_t)N_NODES * sizeof(int), stream);
  hipMemsetAsync(S, 0, 16 * sizeof(float), stream);

  const dim3 B(256);
  const int nodeBlocks = (N_NODES + 255) / 256;  // 196
  const int edgeBlocks = (N_EDGES + 255) / 256;  // 3125

  k_qkv<<<dim3(nodeBlocks, 3), B, 0, stream>>>(x, Wq, bq, Wk, bk, Wv, bv, q, k, v);
  k_hist<<<dim3(edgeBlocks), B, 0, stream>>>(edst, deg);
  k_scan_a<<<dim3(nodeBlocks), B, 0, stream>>>(deg, bsum);
  k_scan_b<<<dim3(1), B, 0, stream>>>(bsum, nodeBlocks);
  k_scan_c<<<dim3(nodeBlocks), B, 0, stream>>>(deg, bsum, rowptr, woff);
  k_scatter<<<dim3(edgeBlocks), B, 0, stream>>>(edst, woff, eidp);
  k_edge_pre<<<dim3(3125), B, 0, stream>>>(esrc, edst, ea, q, k, v, We, be, msg, S);
  k_gather_sum<<<dim3(2048), B, 0, stream>>>(rowptr, eidp, msg, q, k, v, be, osum, cnt, S);
  k_ln1<<<dim3(nodeBlocks), B, 0, stream>>>(osum, cnt, S, x, Wo, bo, g1, b1, h);
  k_ffn1<<<dim3(nodeBlocks), B, 0, stream>>>(h, Wf1, bf1, f1);
  k_ffn2<<<dim3(nodeBlocks), B, 0, stream>>>(f1, h, Wf2, bf2, g2, b2, out);
}

// Round 6
// 539.066 us; speedup vs baseline: 1.4878x; 1.4878x over previous
//
#include <hip/hip_runtime.h>
#include <hip/hip_bf16.h>
#include <math.h>

#define N_NODES 50000
#define N_EDGES 800000
#define D 64
#define ED 32

// ws layout (float-slot offsets). Total ~34.5M slots = 138.0 MB.
#define Q_OFF    0          // bf16 q (1.6M slots)
#define K_OFF    1600000    // bf16 k
#define V_OFF    3200000    // bf16 v
#define EE_OFF   4800000    // bf16 ee: 800k x 64 = 25.6M slots
#define OS_OFF   30400000   // f32 osum 3.2M
#define CNT_OFF  33600000   // 50k: serves as deg -> woff -> cnt (sequential reuse)
#define S_OFF    33650000   // 16
#define RP_OFF   33650016   // 50,001 ints
#define EIDP_OFF 33700020   // 800k ints
#define BSUM_OFF 34500020   // 256 ints
// aliases (dead ranges reused):
#define H_OFF    0          // h f32 3.2M over q/k/v (dead after gather)
#define F1_OFF   EE_OFF     // f1 f32 6.4M over ee (dead after gather)

__device__ __forceinline__ ushort f2bf(float f) {
  uint u = __float_as_uint(f);
  uint r = (u + 0x7FFFu + ((u >> 16) & 1u)) >> 16;
  return (ushort)r;
}
__device__ __forceinline__ float rlane(float v, int l) {
  return __uint_as_float(__builtin_amdgcn_readlane(__float_as_uint(v), l));
}
__device__ __forceinline__ void unpack8(uint4 u, float (&f)[8]) {
  f[0] = __uint_as_float(u.x << 16); f[1] = __uint_as_float(u.x & 0xffff0000u);
  f[2] = __uint_as_float(u.y << 16); f[3] = __uint_as_float(u.y & 0xffff0000u);
  f[4] = __uint_as_float(u.z << 16); f[5] = __uint_as_float(u.z & 0xffff0000u);
  f[6] = __uint_as_float(u.w << 16); f[7] = __uint_as_float(u.w & 0xffff0000u);
}

// ---------------- QKV: lane=feature GEMV, W column in VGPRs, x via readlane ----------------
__global__ __launch_bounds__(256) void k_qkv_rl(
    const float* __restrict__ x,
    const float* __restrict__ Wq, const float* __restrict__ bq,
    const float* __restrict__ Wk, const float* __restrict__ bk,
    const float* __restrict__ Wv, const float* __restrict__ bv,
    ushort* __restrict__ q, ushort* __restrict__ k, ushort* __restrict__ v) {
  const float* W; const float* b; ushort* o;
  if (blockIdx.y == 0)      { W = Wq; b = bq; o = q; }
  else if (blockIdx.y == 1) { W = Wk; b = bk; o = k; }
  else                      { W = Wv; b = bv; o = v; }
  const int lane = threadIdx.x & 63;
  const int wid  = threadIdx.x >> 6;
  float wcol[64];
#pragma unroll
  for (int j = 0; j < 64; ++j) wcol[j] = W[j * 64 + lane];
  const float bl = b[lane];
  const int nw = gridDim.x * 4;
  for (int n = blockIdx.x * 4 + wid; n < N_NODES; n += nw) {
    const float xr = x[(size_t)n * 64 + lane];
    float acc = bl;
#pragma unroll
    for (int j = 0; j < 64; ++j) acc = fmaf(rlane(xr, j), wcol[j], acc);
    o[(size_t)n * 64 + lane] = f2bf(acc);
  }
}

// ---------------- ee GEMM: ee[e] = ea[e] @ We + be (bf16 out, original order) ----------------
#define EERL(SRC, LI, JJ) { acc = fmaf(rlane(SRC, LI), wec[JJ], acc); }
__global__ __launch_bounds__(256) void k_ee(
    const float* __restrict__ ea, const float* __restrict__ We,
    const float* __restrict__ be, ushort* __restrict__ ee) {
  const int lane = threadIdx.x & 63;
  const int wid  = threadIdx.x >> 6;
  float wec[32];
#pragma unroll
  for (int i = 0; i < 32; ++i) wec[i] = We[i * 64 + lane];
  const float bel = be[lane];
  const int nchunk = N_EDGES / 32;  // 25000 exact
  const int nw = gridDim.x * 4;
  for (int c = blockIdx.x * 4 + wid; c < nchunk; c += nw) {
    const int base = c * 32;
    const float4* g = reinterpret_cast<const float4*>(ea + (size_t)base * 32);
    const int fi = (lane >> 1) * 8 + (lane & 1) * 4;
    const float4 c0 = g[fi], c1 = g[fi + 1], c2 = g[fi + 2], c3 = g[fi + 3];
    ushort* op = ee + (size_t)base * 64 + lane;
    for (int e = 0; e < 32; ++e) {
      const int l0 = 2 * e, l1 = 2 * e + 1;
      float acc = bel;
      EERL(c0.x, l0, 0)  EERL(c0.y, l0, 1)  EERL(c0.z, l0, 2)  EERL(c0.w, l0, 3)
      EERL(c1.x, l0, 4)  EERL(c1.y, l0, 5)  EERL(c1.z, l0, 6)  EERL(c1.w, l0, 7)
      EERL(c2.x, l0, 8)  EERL(c2.y, l0, 9)  EERL(c2.z, l0, 10) EERL(c2.w, l0, 11)
      EERL(c3.x, l0, 12) EERL(c3.y, l0, 13) EERL(c3.z, l0, 14) EERL(c3.w, l0, 15)
      EERL(c0.x, l1, 16) EERL(c0.y, l1, 17) EERL(c0.z, l1, 18) EERL(c0.w, l1, 19)
      EERL(c1.x, l1, 20) EERL(c1.y, l1, 21) EERL(c1.z, l1, 22) EERL(c1.w, l1, 23)
      EERL(c2.x, l1, 24) EERL(c2.y, l1, 25) EERL(c2.z, l1, 26) EERL(c2.w, l1, 27)
      EERL(c3.x, l1, 28) EERL(c3.y, l1, 29) EERL(c3.z, l1, 30) EERL(c3.w, l1, 31)
      op[(size_t)e * 64] = f2bf(acc);
    }
  }
}

// ---------------- CSR build ----------------
__global__ __launch_bounds__(256) void k_hist(const int* __restrict__ edst,
                                              int* __restrict__ deg) {
  const int i = blockIdx.x * 256 + threadIdx.x;
  if (i < N_EDGES) atomicAdd(&deg[edst[i]], 1);
}

__global__ __launch_bounds__(256) void k_scan_a(const int* __restrict__ deg,
                                                int* __restrict__ bsum) {
  __shared__ int lds[256];
  const int i = blockIdx.x * 256 + threadIdx.x;
  lds[threadIdx.x] = (i < N_NODES) ? deg[i] : 0;
  __syncthreads();
  for (int s = 128; s > 0; s >>= 1) {
    if (threadIdx.x < s) lds[threadIdx.x] += lds[threadIdx.x + s];
    __syncthreads();
  }
  if (threadIdx.x == 0) bsum[blockIdx.x] = lds[0];
}

__global__ __launch_bounds__(256) void k_scan_b(int* __restrict__ bsum, int nb) {
  __shared__ int lds[256];
  const int t = threadIdx.x;
  const int d = (t < nb) ? bsum[t] : 0;
  lds[t] = d;
  __syncthreads();
  for (int off = 1; off < 256; off <<= 1) {
    const int val = (t >= off) ? lds[t - off] : 0;
    __syncthreads();
    lds[t] += val;
    __syncthreads();
  }
  if (t < nb) bsum[t] = lds[t] - d;  // exclusive
}

__global__ __launch_bounds__(256) void k_scan_c(const int* __restrict__ deg,
                                                const int* __restrict__ bsum,
                                                int* __restrict__ rowptr,
                                                int* __restrict__ woff) {
  __shared__ int lds[256];
  const int i = blockIdx.x * 256 + threadIdx.x;
  const int d = (i < N_NODES) ? deg[i] : 0;
  lds[threadIdx.x] = d;
  __syncthreads();
  for (int off = 1; off < 256; off <<= 1) {
    const int val = (threadIdx.x >= off) ? lds[threadIdx.x - off] : 0;
    __syncthreads();
    lds[threadIdx.x] += val;
    __syncthreads();
  }
  const int ex = bsum[blockIdx.x] + lds[threadIdx.x] - d;
  if (i < N_NODES) { rowptr[i] = ex; woff[i] = ex; }
  if (i == N_NODES - 1) rowptr[N_NODES] = ex + d;
}

__global__ __launch_bounds__(256) void k_scatter(const int* __restrict__ edst,
                                                 int* __restrict__ woff,
                                                 int* __restrict__ eid_perm) {
  const int i = blockIdx.x * 256 + threadIdx.x;
  if (i < N_EDGES) {
    const int pos = atomicAdd(&woff[edst[i]], 1);
    eid_perm[pos] = i;
  }
}

// ---------------- gather: wave per node, lane=(edge-slot, head), in-lane dots ----------------
__global__ __launch_bounds__(256) void k_gather(
    const int* __restrict__ rowptr, const int* __restrict__ eid_perm,
    const int* __restrict__ esrc, const ushort* __restrict__ ee,
    const ushort* __restrict__ qb, const ushort* __restrict__ kb,
    const ushort* __restrict__ vb, const float* __restrict__ be,
    float* __restrict__ osum, float* __restrict__ cnt, float* __restrict__ S) {
  const int lane = threadIdx.x & 63;
  const int wid  = threadIdx.x >> 6;
  const int h = lane & 7, ei = lane >> 3;
  float bes[8];
#pragma unroll
  for (int i = 0; i < 8; ++i) bes[i] = be[h * 8 + i];
  float sacc = 0.f;
  const int nw = gridDim.x * 4;
  for (int n = blockIdx.x * 4 + wid; n < N_NODES; n += nw) {
    const int beg = rowptr[n], end = rowptr[n + 1];
    float qv[8];
    unpack8(*reinterpret_cast<const uint4*>(qb + (size_t)n * 64 + h * 8), qv);
    float macc[8];
#pragma unroll
    for (int i = 0; i < 8; ++i) macc[i] = 0.f;
    if (ei == 0) {  // self loop: ea=0 -> ee=be
      float kv[8], vv[8];
      unpack8(*reinterpret_cast<const uint4*>(kb + (size_t)n * 64 + h * 8), kv);
      unpack8(*reinterpret_cast<const uint4*>(vb + (size_t)n * 64 + h * 8), vv);
      float sc = 0.f;
#pragma unroll
      for (int i = 0; i < 8; ++i) sc = fmaf(qv[i], kv[i] + bes[i], sc);
      const float w = __expf(sc * 0.3535533905932738f);
      sacc += w;
#pragma unroll
      for (int i = 0; i < 8; ++i) macc[i] = w * (vv[i] + bes[i]);
    }
    for (int p = beg + ei; p < end; p += 8) {
      const int eid = eid_perm[p];
      const int src = esrc[eid];
      float ev[8], kv[8], vv[8];
      unpack8(*reinterpret_cast<const uint4*>(ee + (size_t)eid * 64 + h * 8), ev);
      unpack8(*reinterpret_cast<const uint4*>(kb + (size_t)src * 64 + h * 8), kv);
      unpack8(*reinterpret_cast<const uint4*>(vb + (size_t)src * 64 + h * 8), vv);
      float sc = 0.f;
#pragma unroll
      for (int i = 0; i < 8; ++i) sc = fmaf(qv[i], kv[i] + ev[i], sc);
      const float w = __expf(sc * 0.3535533905932738f);
      sacc += w;
#pragma unroll
      for (int i = 0; i < 8; ++i) macc[i] = fmaf(w, vv[i] + ev[i], macc[i]);
    }
#pragma unroll
    for (int i = 0; i < 8; ++i) {
      macc[i] += __shfl_xor(macc[i], 8);
      macc[i] += __shfl_xor(macc[i], 16);
      macc[i] += __shfl_xor(macc[i], 32);
    }
    if (ei == 0) {
      float4 o0 = make_float4(macc[0], macc[1], macc[2], macc[3]);
      float4 o1 = make_float4(macc[4], macc[5], macc[6], macc[7]);
      *reinterpret_cast<float4*>(osum + (size_t)n * 64 + h * 8)     = o0;
      *reinterpret_cast<float4*>(osum + (size_t)n * 64 + h * 8 + 4) = o1;
      if (lane == 0) cnt[n] = (float)(end - beg + 1);
    }
  }
  sacc += __shfl_xor(sacc, 8);
  sacc += __shfl_xor(sacc, 16);
  sacc += __shfl_xor(sacc, 32);
  if (ei == 0) atomicAdd(&S[h], sacc);
}

// ---------------- LN1: (osum scaled) @ Wo + bo, +x, LN -> h ----------------
__global__ __launch_bounds__(256) void k_ln1_rl(
    const float* __restrict__ osum, const float* __restrict__ cnt,
    const float* __restrict__ S, const float* __restrict__ x,
    const float* __restrict__ Wo, const float* __restrict__ bo,
    const float* __restrict__ g1, const float* __restrict__ b1,
    float* __restrict__ h) {
  const int lane = threadIdx.x & 63;
  const int wid  = threadIdx.x >> 6;
  float wcol[64];
#pragma unroll
  for (int j = 0; j < 64; ++j) wcol[j] = Wo[j * 64 + lane];
  const float bl = bo[lane];
  const float gl = g1[lane], b1l = b1[lane];
  const float invS = 1.0f / S[lane >> 3];
  const int nw = gridDim.x * 4;
  for (int n = blockIdx.x * 4 + wid; n < N_NODES; n += nw) {
    const float invc = 1.0f / cnt[n];
    const float val = osum[(size_t)n * 64 + lane] * invS * invc;
    float acc = bl;
#pragma unroll
    for (int j = 0; j < 64; ++j) acc = fmaf(rlane(val, j), wcol[j], acc);
    const float t = x[(size_t)n * 64 + lane] + acc;
    float s = t;
    s += __shfl_xor(s, 1);  s += __shfl_xor(s, 2);  s += __shfl_xor(s, 4);
    s += __shfl_xor(s, 8);  s += __shfl_xor(s, 16); s += __shfl_xor(s, 32);
    const float m = s * (1.0f / 64.0f);
    const float d = t - m;
    float vs = d * d;
    vs += __shfl_xor(vs, 1);  vs += __shfl_xor(vs, 2);  vs += __shfl_xor(vs, 4);
    vs += __shfl_xor(vs, 8);  vs += __shfl_xor(vs, 16); vs += __shfl_xor(vs, 32);
    const float r = rsqrtf(vs * (1.0f / 64.0f) + 1e-5f);
    h[(size_t)n * 64 + lane] = d * r * gl + b1l;
  }
}

// ---------------- FFN1: f1 = gelu(h @ Wf1 + bf1), feature-half per blockIdx.y ----------------
__global__ __launch_bounds__(256) void k_ffn1_rl(
    const float* __restrict__ h, const float* __restrict__ Wf1,
    const float* __restrict__ bf1, float* __restrict__ f1) {
  const int lane = threadIdx.x & 63;
  const int wid  = threadIdx.x >> 6;
  const int f = blockIdx.y * 64 + lane;
  float wcol[64];
#pragma unroll
  for (int j = 0; j < 64; ++j) wcol[j] = Wf1[j * 128 + f];
  const float bl = bf1[f];
  const int nw = gridDim.x * 4;
  for (int n = blockIdx.x * 4 + wid; n < N_NODES; n += nw) {
    const float hr = h[(size_t)n * 64 + lane];
    float acc = bl;
#pragma unroll
    for (int j = 0; j < 64; ++j) acc = fmaf(rlane(hr, j), wcol[j], acc);
    f1[(size_t)n * 128 + f] = 0.5f * acc * (1.0f + erff(acc * 0.7071067811865475f));
  }
}

// ---------------- FFN2 + residual + LN2 -> out ----------------
__global__ __launch_bounds__(256) void k_ffn2_rl(
    const float* __restrict__ f1, const float* __restrict__ h,
    const float* __restrict__ Wf2, const float* __restrict__ bf2,
    const float* __restrict__ g2, const float* __restrict__ b2,
    float* __restrict__ out) {
  const int lane = threadIdx.x & 63;
  const int wid  = threadIdx.x >> 6;
  float wcol[128];
#pragma unroll
  for (int j = 0; j < 128; ++j) wcol[j] = Wf2[j * 64 + lane];
  const float bl = bf2[lane];
  const float gl = g2[lane], b2l = b2[lane];
  const int nw = gridDim.x * 4;
  for (int n = blockIdx.x * 4 + wid; n < N_NODES; n += nw) {
    const float a0 = f1[(size_t)n * 128 + lane];
    const float a1 = f1[(size_t)n * 128 + 64 + lane];
    float acc = bl;
#pragma unroll
    for (int j = 0; j < 64; ++j) acc = fmaf(rlane(a0, j), wcol[j], acc);
#pragma unroll
    for (int j = 0; j < 64; ++j) acc = fmaf(rlane(a1, j), wcol[64 + j], acc);
    const float t = h[(size_t)n * 64 + lane] + acc;
    float s = t;
    s += __shfl_xor(s, 1);  s += __shfl_xor(s, 2);  s += __shfl_xor(s, 4);
    s += __shfl_xor(s, 8);  s += __shfl_xor(s, 16); s += __shfl_xor(s, 32);
    const float m = s * (1.0f / 64.0f);
    const float d = t - m;
    float vs = d * d;
    vs += __shfl_xor(vs, 1);  vs += __shfl_xor(vs, 2);  vs += __shfl_xor(vs, 4);
    vs += __shfl_xor(vs, 8);  vs += __shfl_xor(vs, 16); vs += __shfl_xor(vs, 32);
    const float r = rsqrtf(vs * (1.0f / 64.0f) + 1e-5f);
    out[(size_t)n * 64 + lane] = d * r * gl + b2l;
  }
}

extern "C" void kernel_launch(void* const* d_in, const int* in_sizes, int n_in,
                              void* d_out, int out_size, void* d_ws, size_t ws_size,
                              hipStream_t stream) {
  const float* x    = (const float*)d_in[0];
  const int*   ei   = (const int*)d_in[1];
  const int*   esrc = ei;
  const int*   edst = ei + N_EDGES;
  const float* ea   = (const float*)d_in[2];
  const float* Wq   = (const float*)d_in[3];
  const float* bq   = (const float*)d_in[4];
  const float* Wk   = (const float*)d_in[5];
  const float* bk   = (const float*)d_in[6];
  const float* Wv   = (const float*)d_in[7];
  const float* bv   = (const float*)d_in[8];
  const float* We   = (const float*)d_in[9];
  const float* be   = (const float*)d_in[10];
  const float* Wo   = (const float*)d_in[11];
  const float* bo   = (const float*)d_in[12];
  const float* g1   = (const float*)d_in[13];
  const float* b1   = (const float*)d_in[14];
  const float* g2   = (const float*)d_in[15];
  const float* b2   = (const float*)d_in[16];
  const float* Wf1  = (const float*)d_in[17];
  const float* bf1  = (const float*)d_in[18];
  const float* Wf2  = (const float*)d_in[19];
  const float* bf2  = (const float*)d_in[20];

  float* ws    = (float*)d_ws;
  ushort* q    = (ushort*)(ws + Q_OFF);
  ushort* k    = (ushort*)(ws + K_OFF);
  ushort* v    = (ushort*)(ws + V_OFF);
  ushort* eeb  = (ushort*)(ws + EE_OFF);
  float* osum  = ws + OS_OFF;
  float* cnt   = ws + CNT_OFF;   // also deg / woff (sequential lifetimes)
  float* S     = ws + S_OFF;
  int*   rowptr = (int*)(ws + RP_OFF);
  int*   eidp   = (int*)(ws + EIDP_OFF);
  int*   bsum   = (int*)(ws + BSUM_OFF);
  int*   deg    = (int*)cnt;
  int*   woff   = (int*)cnt;
  float* h     = ws + H_OFF;
  float* f1    = ws + F1_OFF;
  float* out   = (float*)d_out;

  hipMemsetAsync(deg, 0, (size_t)N_NODES * sizeof(int), stream);
  hipMemsetAsync(S, 0, 16 * sizeof(float), stream);

  const dim3 B(256);
  const int nodeBlocks = (N_NODES + 255) / 256;  // 196
  const int edgeBlocks = (N_EDGES + 255) / 256;  // 3125

  k_qkv_rl<<<dim3(256, 3), B, 0, stream>>>(x, Wq, bq, Wk, bk, Wv, bv, q, k, v);
  k_ee<<<dim3(1024), B, 0, stream>>>(ea, We, be, eeb);
  k_hist<<<dim3(edgeBlocks), B, 0, stream>>>(edst, deg);
  k_scan_a<<<dim3(nodeBlocks), B, 0, stream>>>(deg, bsum);
  k_scan_b<<<dim3(1), B, 0, stream>>>(bsum, nodeBlocks);
  k_scan_c<<<dim3(nodeBlocks), B, 0, stream>>>(deg, bsum, rowptr, woff);
  k_scatter<<<dim3(edgeBlocks), B, 0, stream>>>(edst, woff, eidp);
  k_gather<<<dim3(1024), B, 0, stream>>>(rowptr, eidp, esrc, eeb, q, k, v, be, osum, cnt, S);
  k_ln1_rl<<<dim3(256), B, 0, stream>>>(osum, cnt, S, x, Wo, bo, g1, b1, h);
  k_ffn1_rl<<<dim3(256, 2), B, 0, stream>>>(h, Wf1, bf1, f1);
  k_ffn2_rl<<<dim3(256), B, 0, stream>>>(f1, h, Wf2, bf2, g2, b2, out);
}

// Round 7
// 502.570 us; speedup vs baseline: 1.5958x; 1.0726x over previous
//
#include <hip/hip_runtime.h>
#include <hip/hip_bf16.h>
#include <math.h>

#define N_NODES 50000
#define N_EDGES 800000
#define D 64
#define ED 32

// ws layout (float-slot offsets). Total 33,700,274 slots = 134.8 MB.
#define Q_OFF    0          // bf16 q (1.6M slots)
#define K_OFF    1600000    // bf16 k
#define V_OFF    3200000    // bf16 v
#define EE_OFF   4800000    // bf16 ee, dst-sorted: 800k x 64 = 25.6M slots
#define OS_OFF   30400000   // bf16 osum: 1.6M slots
#define CNT_OFF  32000000   // 50k: deg -> woff -> cnt (sequential reuse); WET aliases head
#define S_OFF    32050000   // 16
#define RP_OFF   32050016   // 50,001 (+1 pad)
#define SRCP_OFF 32100018   // 800k ints (src per sorted position)
#define EIDP_OFF 32900018   // 800k ints (orig edge id per sorted position)
#define BSUM_OFF 33700018   // 256 ints
#define WET_OFF  CNT_OFF    // 2048 f32 WeT[64][32]; alive only between k_wet and k_ee
// aliases (dead ranges reused):
#define H_OFF    0          // h f32 3.2M over q/k/v (dead after gather)
#define F1_OFF   EE_OFF     // f1 f32 6.4M over ee (dead after gather)

__device__ __forceinline__ ushort f2bf(float f) {
  uint u = __float_as_uint(f);
  uint r = (u + 0x7FFFu + ((u >> 16) & 1u)) >> 16;
  return (ushort)r;
}
__device__ __forceinline__ float rlane(float v, int l) {
  return __uint_as_float(__builtin_amdgcn_readlane(__float_as_uint(v), l));
}
__device__ __forceinline__ void unpack8(uint4 u, float (&f)[8]) {
  f[0] = __uint_as_float(u.x << 16); f[1] = __uint_as_float(u.x & 0xffff0000u);
  f[2] = __uint_as_float(u.y << 16); f[3] = __uint_as_float(u.y & 0xffff0000u);
  f[4] = __uint_as_float(u.z << 16); f[5] = __uint_as_float(u.z & 0xffff0000u);
  f[6] = __uint_as_float(u.w << 16); f[7] = __uint_as_float(u.w & 0xffff0000u);
}

// ---------------- QKV: lane=feature GEMV, W column in VGPRs, x via readlane ----------------
__global__ __launch_bounds__(256) void k_qkv_rl(
    const float* __restrict__ x,
    const float* __restrict__ Wq, const float* __restrict__ bq,
    const float* __restrict__ Wk, const float* __restrict__ bk,
    const float* __restrict__ Wv, const float* __restrict__ bv,
    ushort* __restrict__ q, ushort* __restrict__ k, ushort* __restrict__ v) {
  const float* W; const float* b; ushort* o;
  if (blockIdx.y == 0)      { W = Wq; b = bq; o = q; }
  else if (blockIdx.y == 1) { W = Wk; b = bk; o = k; }
  else                      { W = Wv; b = bv; o = v; }
  const int lane = threadIdx.x & 63;
  const int wid  = threadIdx.x >> 6;
  float wcol[64];
#pragma unroll
  for (int j = 0; j < 64; ++j) wcol[j] = W[j * 64 + lane];
  const float bl = b[lane];
  const int nw = gridDim.x * 4;
  for (int n = blockIdx.x * 4 + wid; n < N_NODES; n += nw) {
    const float xr = x[(size_t)n * 64 + lane];
    float acc = bl;
#pragma unroll
    for (int j = 0; j < 64; ++j) acc = fmaf(rlane(xr, j), wcol[j], acc);
    o[(size_t)n * 64 + lane] = f2bf(acc);
  }
}

// ---------------- tiny: WeT[f][k] = We[k][f] ----------------
__global__ __launch_bounds__(256) void k_wet(const float* __restrict__ We,
                                             float* __restrict__ wet) {
  const int t = blockIdx.x * 256 + threadIdx.x;
  if (t < 2048) { const int f = t >> 5, k2 = t & 31; wet[t] = We[k2 * 64 + f]; }
}

// ---------------- CSR build ----------------
__global__ __launch_bounds__(256) void k_hist(const int* __restrict__ edst,
                                              int* __restrict__ deg) {
  const int i = blockIdx.x * 256 + threadIdx.x;
  if (i < N_EDGES) atomicAdd(&deg[edst[i]], 1);
}

__global__ __launch_bounds__(256) void k_scan_a(const int* __restrict__ deg,
                                                int* __restrict__ bsum) {
  __shared__ int lds[256];
  const int i = blockIdx.x * 256 + threadIdx.x;
  lds[threadIdx.x] = (i < N_NODES) ? deg[i] : 0;
  __syncthreads();
  for (int s = 128; s > 0; s >>= 1) {
    if (threadIdx.x < s) lds[threadIdx.x] += lds[threadIdx.x + s];
    __syncthreads();
  }
  if (threadIdx.x == 0) bsum[blockIdx.x] = lds[0];
}

__global__ __launch_bounds__(256) void k_scan_b(int* __restrict__ bsum, int nb) {
  __shared__ int lds[256];
  const int t = threadIdx.x;
  const int d = (t < nb) ? bsum[t] : 0;
  lds[t] = d;
  __syncthreads();
  for (int off = 1; off < 256; off <<= 1) {
    const int val = (t >= off) ? lds[t - off] : 0;
    __syncthreads();
    lds[t] += val;
    __syncthreads();
  }
  if (t < nb) bsum[t] = lds[t] - d;  // exclusive
}

__global__ __launch_bounds__(256) void k_scan_c(const int* __restrict__ deg,
                                                const int* __restrict__ bsum,
                                                int* __restrict__ rowptr,
                                                int* __restrict__ woff) {
  __shared__ int lds[256];
  const int i = blockIdx.x * 256 + threadIdx.x;
  const int d = (i < N_NODES) ? deg[i] : 0;
  lds[threadIdx.x] = d;
  __syncthreads();
  for (int off = 1; off < 256; off <<= 1) {
    const int val = (threadIdx.x >= off) ? lds[threadIdx.x - off] : 0;
    __syncthreads();
    lds[threadIdx.x] += val;
    __syncthreads();
  }
  const int ex = bsum[blockIdx.x] + lds[threadIdx.x] - d;
  if (i < N_NODES) { rowptr[i] = ex; woff[i] = ex; }
  if (i == N_NODES - 1) rowptr[N_NODES] = ex + d;
}

__global__ __launch_bounds__(256) void k_scatter(const int* __restrict__ esrc,
                                                 const int* __restrict__ edst,
                                                 int* __restrict__ woff,
                                                 int* __restrict__ srcp,
                                                 int* __restrict__ eidp) {
  const int i = blockIdx.x * 256 + threadIdx.x;
  if (i < N_EDGES) {
    const int pos = atomicAdd(&woff[edst[i]], 1);
    srcp[pos] = esrc[i];
    eidp[pos] = i;
  }
}

// ---------------- ee GEMM: thread=sorted position, scalar-broadcast We ----------------
// ee[j] = ea[eidp[j]] @ We + be, written sequentially (dst-sorted order).
__global__ __launch_bounds__(256) void k_ee(
    const int* __restrict__ eidp, const float* __restrict__ ea,
    const float* __restrict__ wet, const float* __restrict__ be,
    ushort* __restrict__ ee) {
  const int j = blockIdx.x * 256 + threadIdx.x;  // 0..800k, exact grid
  const int eid = eidp[j];
  const float4* ar = reinterpret_cast<const float4*>(ea + (size_t)eid * 32);
  float r[32];
#pragma unroll
  for (int i4 = 0; i4 < 8; ++i4) {
    const float4 t = ar[i4];
    r[i4 * 4 + 0] = t.x; r[i4 * 4 + 1] = t.y;
    r[i4 * 4 + 2] = t.z; r[i4 * 4 + 3] = t.w;
  }
  uint4* orow = reinterpret_cast<uint4*>(ee + (size_t)j * 64);
  for (int f8 = 0; f8 < 8; ++f8) {
    uint pk[4];
#pragma unroll
    for (int fp = 0; fp < 4; ++fp) {
      float a2[2];
#pragma unroll
      for (int fe = 0; fe < 2; ++fe) {
        const int f = f8 * 8 + fp * 2 + fe;
        const float* wf = wet + f * 32;   // wave-uniform -> scalar loads
        float acc = be[f];
#pragma unroll
        for (int kk = 0; kk < 32; ++kk) acc = fmaf(r[kk], wf[kk], acc);
        a2[fe] = acc;
      }
      pk[fp] = (uint)f2bf(a2[0]) | ((uint)f2bf(a2[1]) << 16);
    }
    orow[f8] = make_uint4(pk[0], pk[1], pk[2], pk[3]);
  }
}

// ---------------- gather: wave per node, lane=(edge-slot, head), streaming ee ----------------
__global__ __launch_bounds__(256) void k_gather(
    const int* __restrict__ rowptr, const int* __restrict__ srcp,
    const ushort* __restrict__ ee,
    const ushort* __restrict__ qb, const ushort* __restrict__ kb,
    const ushort* __restrict__ vb, const float* __restrict__ be,
    ushort* __restrict__ osum, float* __restrict__ cnt, float* __restrict__ S) {
  const int lane = threadIdx.x & 63;
  const int wid  = threadIdx.x >> 6;
  const int h = lane & 7, ei = lane >> 3;
  float bes[8];
#pragma unroll
  for (int i = 0; i < 8; ++i) bes[i] = be[h * 8 + i];
  float sacc = 0.f;
  const int nw = gridDim.x * 4;
  for (int n = blockIdx.x * 4 + wid; n < N_NODES; n += nw) {
    const int beg = rowptr[n], end = rowptr[n + 1];
    float qv[8];
    unpack8(*reinterpret_cast<const uint4*>(qb + (size_t)n * 64 + h * 8), qv);
    float macc[8];
#pragma unroll
    for (int i = 0; i < 8; ++i) macc[i] = 0.f;
    if (ei == 0) {  // self loop: ea=0 -> ee=be
      float kv[8], vv[8];
      unpack8(*reinterpret_cast<const uint4*>(kb + (size_t)n * 64 + h * 8), kv);
      unpack8(*reinterpret_cast<const uint4*>(vb + (size_t)n * 64 + h * 8), vv);
      float sc = 0.f;
#pragma unroll
      for (int i = 0; i < 8; ++i) sc = fmaf(qv[i], kv[i] + bes[i], sc);
      const float w = __expf(sc * 0.3535533905932738f);
      sacc += w;
#pragma unroll
      for (int i = 0; i < 8; ++i) macc[i] = w * (vv[i] + bes[i]);
    }
    int p = beg + ei;
    int src = (p < end) ? srcp[p] : 0;
    for (; p < end; p += 8) {
      const int nsrc = (p + 8 < end) ? srcp[p + 8] : 0;
      float ev[8], kv[8], vv[8];
      unpack8(*reinterpret_cast<const uint4*>(ee + (size_t)p * 64 + h * 8), ev);
      unpack8(*reinterpret_cast<const uint4*>(kb + (size_t)src * 64 + h * 8), kv);
      unpack8(*reinterpret_cast<const uint4*>(vb + (size_t)src * 64 + h * 8), vv);
      float sc = 0.f;
#pragma unroll
      for (int i = 0; i < 8; ++i) sc = fmaf(qv[i], kv[i] + ev[i], sc);
      const float w = __expf(sc * 0.3535533905932738f);
      sacc += w;
#pragma unroll
      for (int i = 0; i < 8; ++i) macc[i] = fmaf(w, vv[i] + ev[i], macc[i]);
      src = nsrc;
    }
#pragma unroll
    for (int i = 0; i < 8; ++i) {
      macc[i] += __shfl_xor(macc[i], 8);
      macc[i] += __shfl_xor(macc[i], 16);
      macc[i] += __shfl_xor(macc[i], 32);
    }
    if (ei == 0) {
      uint pk[4];
#pragma unroll
      for (int i = 0; i < 4; ++i)
        pk[i] = (uint)f2bf(macc[2 * i]) | ((uint)f2bf(macc[2 * i + 1]) << 16);
      *reinterpret_cast<uint4*>(osum + (size_t)n * 64 + h * 8) =
          make_uint4(pk[0], pk[1], pk[2], pk[3]);
      if (lane == 0) cnt[n] = (float)(end - beg + 1);
    }
  }
  sacc += __shfl_xor(sacc, 8);
  sacc += __shfl_xor(sacc, 16);
  sacc += __shfl_xor(sacc, 32);
  if (ei == 0) atomicAdd(&S[h], sacc);
}

// ---------------- LN1: (osum scaled) @ Wo + bo, +x, LN -> h ----------------
__global__ __launch_bounds__(256) void k_ln1_rl(
    const ushort* __restrict__ osum, const float* __restrict__ cnt,
    const float* __restrict__ S, const float* __restrict__ x,
    const float* __restrict__ Wo, const float* __restrict__ bo,
    const float* __restrict__ g1, const float* __restrict__ b1,
    float* __restrict__ h) {
  const int lane = threadIdx.x & 63;
  const int wid  = threadIdx.x >> 6;
  float wcol[64];
#pragma unroll
  for (int j = 0; j < 64; ++j) wcol[j] = Wo[j * 64 + lane];
  const float bl = bo[lane];
  const float gl = g1[lane], b1l = b1[lane];
  const float invS = 1.0f / S[lane >> 3];
  const int nw = gridDim.x * 4;
  for (int n = blockIdx.x * 4 + wid; n < N_NODES; n += nw) {
    const float invc = 1.0f / cnt[n];
    const float val =
        __uint_as_float(((uint)osum[(size_t)n * 64 + lane]) << 16) * invS * invc;
    float acc = bl;
#pragma unroll
    for (int j = 0; j < 64; ++j) acc = fmaf(rlane(val, j), wcol[j], acc);
    const float t = x[(size_t)n * 64 + lane] + acc;
    float s = t;
    s += __shfl_xor(s, 1);  s += __shfl_xor(s, 2);  s += __shfl_xor(s, 4);
    s += __shfl_xor(s, 8);  s += __shfl_xor(s, 16); s += __shfl_xor(s, 32);
    const float m = s * (1.0f / 64.0f);
    const float d = t - m;
    float vs = d * d;
    vs += __shfl_xor(vs, 1);  vs += __shfl_xor(vs, 2);  vs += __shfl_xor(vs, 4);
    vs += __shfl_xor(vs, 8);  vs += __shfl_xor(vs, 16); vs += __shfl_xor(vs, 32);
    const float r = rsqrtf(vs * (1.0f / 64.0f) + 1e-5f);
    h[(size_t)n * 64 + lane] = d * r * gl + b1l;
  }
}

// ---------------- FFN1: f1 = gelu(h @ Wf1 + bf1), feature-half per blockIdx.y ----------------
__global__ __launch_bounds__(256) void k_ffn1_rl(
    const float* __restrict__ h, const float* __restrict__ Wf1,
    const float* __restrict__ bf1, float* __restrict__ f1) {
  const int lane = threadIdx.x & 63;
  const int wid  = threadIdx.x >> 6;
  const int f = blockIdx.y * 64 + lane;
  float wcol[64];
#pragma unroll
  for (int j = 0; j < 64; ++j) wcol[j] = Wf1[j * 128 + f];
  const float bl = bf1[f];
  const int nw = gridDim.x * 4;
  for (int n = blockIdx.x * 4 + wid; n < N_NODES; n += nw) {
    const float hr = h[(size_t)n * 64 + lane];
    float acc = bl;
#pragma unroll
    for (int j = 0; j < 64; ++j) acc = fmaf(rlane(hr, j), wcol[j], acc);
    f1[(size_t)n * 128 + f] = 0.5f * acc * (1.0f + erff(acc * 0.7071067811865475f));
  }
}

// ---------------- FFN2 + residual + LN2 -> out ----------------
__global__ __launch_bounds__(256) void k_ffn2_rl(
    const float* __restrict__ f1, const float* __restrict__ h,
    const float* __restrict__ Wf2, const float* __restrict__ bf2,
    const float* __restrict__ g2, const float* __restrict__ b2,
    float* __restrict__ out) {
  const int lane = threadIdx.x & 63;
  const int wid  = threadIdx.x >> 6;
  float wcol[128];
#pragma unroll
  for (int j = 0; j < 128; ++j) wcol[j] = Wf2[j * 64 + lane];
  const float bl = bf2[lane];
  const float gl = g2[lane], b2l = b2[lane];
  const int nw = gridDim.x * 4;
  for (int n = blockIdx.x * 4 + wid; n < N_NODES; n += nw) {
    const float a0 = f1[(size_t)n * 128 + lane];
    const float a1 = f1[(size_t)n * 128 + 64 + lane];
    float acc = bl;
#pragma unroll
    for (int j = 0; j < 64; ++j) acc = fmaf(rlane(a0, j), wcol[j], acc);
#pragma unroll
    for (int j = 0; j < 64; ++j) acc = fmaf(rlane(a1, j), wcol[64 + j], acc);
    const float t = h[(size_t)n * 64 + lane] + acc;
    float s = t;
    s += __shfl_xor(s, 1);  s += __shfl_xor(s, 2);  s += __shfl_xor(s, 4);
    s += __shfl_xor(s, 8);  s += __shfl_xor(s, 16); s += __shfl_xor(s, 32);
    const float m = s * (1.0f / 64.0f);
    const float d = t - m;
    float vs = d * d;
    vs += __shfl_xor(vs, 1);  vs += __shfl_xor(vs, 2);  vs += __shfl_xor(vs, 4);
    vs += __shfl_xor(vs, 8);  vs += __shfl_xor(vs, 16); vs += __shfl_xor(vs, 32);
    const float r = rsqrtf(vs * (1.0f / 64.0f) + 1e-5f);
    out[(size_t)n * 64 + lane] = d * r * gl + b2l;
  }
}

extern "C" void kernel_launch(void* const* d_in, const int* in_sizes, int n_in,
                              void* d_out, int out_size, void* d_ws, size_t ws_size,
                              hipStream_t stream) {
  const float* x    = (const float*)d_in[0];
  const int*   ei   = (const int*)d_in[1];
  const int*   esrc = ei;
  const int*   edst = ei + N_EDGES;
  const float* ea   = (const float*)d_in[2];
  const float* Wq   = (const float*)d_in[3];
  const float* bq   = (const float*)d_in[4];
  const float* Wk   = (const float*)d_in[5];
  const float* bk   = (const float*)d_in[6];
  const float* Wv   = (const float*)d_in[7];
  const float* bv   = (const float*)d_in[8];
  const float* We   = (const float*)d_in[9];
  const float* be   = (const float*)d_in[10];
  const float* Wo   = (const float*)d_in[11];
  const float* bo   = (const float*)d_in[12];
  const float* g1   = (const float*)d_in[13];
  const float* b1   = (const float*)d_in[14];
  const float* g2   = (const float*)d_in[15];
  const float* b2   = (const float*)d_in[16];
  const float* Wf1  = (const float*)d_in[17];
  const float* bf1  = (const float*)d_in[18];
  const float* Wf2  = (const float*)d_in[19];
  const float* bf2  = (const float*)d_in[20];

  float* ws    = (float*)d_ws;
  ushort* q    = (ushort*)(ws + Q_OFF);
  ushort* k    = (ushort*)(ws + K_OFF);
  ushort* v    = (ushort*)(ws + V_OFF);
  ushort* eeb  = (ushort*)(ws + EE_OFF);
  ushort* osum = (ushort*)(ws + OS_OFF);
  float* cnt   = ws + CNT_OFF;   // also deg / woff / WeT (sequential lifetimes)
  float* S     = ws + S_OFF;
  int*   rowptr = (int*)(ws + RP_OFF);
  int*   srcp   = (int*)(ws + SRCP_OFF);
  int*   eidp   = (int*)(ws + EIDP_OFF);
  int*   bsum   = (int*)(ws + BSUM_OFF);
  float* wet    = ws + WET_OFF;
  int*   deg    = (int*)cnt;
  int*   woff   = (int*)cnt;
  float* h     = ws + H_OFF;
  float* f1    = ws + F1_OFF;
  float* out   = (float*)d_out;

  hipMemsetAsync(deg, 0, (size_t)N_NODES * sizeof(int), stream);
  hipMemsetAsync(S, 0, 16 * sizeof(float), stream);

  const dim3 B(256);
  const int nodeBlocks = (N_NODES + 255) / 256;  // 196
  const int edgeBlocks = (N_EDGES + 255) / 256;  // 3125

  k_qkv_rl<<<dim3(256, 3), B, 0, stream>>>(x, Wq, bq, Wk, bk, Wv, bv, q, k, v);
  k_hist<<<dim3(edgeBlocks), B, 0, stream>>>(edst, deg);
  k_scan_a<<<dim3(nodeBlocks), B, 0, stream>>>(deg, bsum);
  k_scan_b<<<dim3(1), B, 0, stream>>>(bsum, nodeBlocks);
  k_scan_c<<<dim3(nodeBlocks), B, 0, stream>>>(deg, bsum, rowptr, woff);
  k_scatter<<<dim3(edgeBlocks), B, 0, stream>>>(esrc, edst, woff, srcp, eidp);
  k_wet<<<dim3(8), B, 0, stream>>>(We, wet);
  k_ee<<<dim3(edgeBlocks), B, 0, stream>>>(eidp, ea, wet, be, eeb);
  k_gather<<<dim3(1024), B, 0, stream>>>(rowptr, srcp, eeb, q, k, v, be, osum, cnt, S);
  k_ln1_rl<<<dim3(256), B, 0, stream>>>(osum, cnt, S, x, Wo, bo, g1, b1, h);
  k_ffn1_rl<<<dim3(256, 2), B, 0, stream>>>(h, Wf1, bf1, f1);
  k_ffn2_rl<<<dim3(256), B, 0, stream>>>(f1, h, Wf2, bf2, g2, b2, out);
}

// Round 8
// 406.362 us; speedup vs baseline: 1.9737x; 1.2368x over previous
//
#include <hip/hip_runtime.h>
#include <hip/hip_bf16.h>
#include <math.h>

#define N_NODES 50000
#define N_EDGES 800000
#define D 64
#define ED 32

// ws layout (float-slot offsets). Total 33,700,274 slots = 134.8 MB.
#define Q_OFF    0          // bf16 q (1.6M slots)
#define K_OFF    1600000    // bf16 k
#define V_OFF    3200000    // bf16 v
#define EE_OFF   4800000    // bf16 ee, dst-sorted: 800k x 64 = 25.6M slots
#define OS_OFF   30400000   // bf16 osum: 1.6M slots
#define CNT_OFF  32000000   // 50k: deg -> woff -> cnt (sequential reuse)
#define S_OFF    32050000   // 16
#define RP_OFF   32050016   // 50,001 (+1 pad)
#define SRCP_OFF 32100018   // 800k ints (src per sorted position)
#define EIDP_OFF 32900018   // 800k ints (orig edge id per sorted position)
#define BSUM_OFF 33700018   // 256 ints
// aliases (dead ranges reused):
#define H_OFF    0          // h f32 3.2M over q/k/v (dead after gather)
#define F1_OFF   EE_OFF     // f1 f32 6.4M over ee (dead after gather)

typedef __bf16 bf16x8 __attribute__((ext_vector_type(8)));
typedef float  f32x4  __attribute__((ext_vector_type(4)));

__device__ __forceinline__ ushort f2bf(float f) {
  uint u = __float_as_uint(f);
  uint r = (u + 0x7FFFu + ((u >> 16) & 1u)) >> 16;
  return (ushort)r;
}
__device__ __forceinline__ float rlane(float v, int l) {
  return __uint_as_float(__builtin_amdgcn_readlane(__float_as_uint(v), l));
}
__device__ __forceinline__ void unpack8(uint4 u, float (&f)[8]) {
  f[0] = __uint_as_float(u.x << 16); f[1] = __uint_as_float(u.x & 0xffff0000u);
  f[2] = __uint_as_float(u.y << 16); f[3] = __uint_as_float(u.y & 0xffff0000u);
  f[4] = __uint_as_float(u.z << 16); f[5] = __uint_as_float(u.z & 0xffff0000u);
  f[6] = __uint_as_float(u.w << 16); f[7] = __uint_as_float(u.w & 0xffff0000u);
}
__device__ __forceinline__ bf16x8 pack_bf8(float4 a, float4 b) {
  bf16x8 r;
  r[0] = (__bf16)a.x; r[1] = (__bf16)a.y; r[2] = (__bf16)a.z; r[3] = (__bf16)a.w;
  r[4] = (__bf16)b.x; r[5] = (__bf16)b.y; r[6] = (__bf16)b.z; r[7] = (__bf16)b.w;
  return r;
}

// ---------------- QKV via MFMA: 16 nodes/tile, q/k/v fused ----------------
// A = W^T tile (feature-major), B = x rows, D[f=(kg)*4+j][item=l%16].
__global__ __launch_bounds__(256) void k_qkv_mfma(
    const float* __restrict__ x,
    const float* __restrict__ Wq, const float* __restrict__ bq,
    const float* __restrict__ Wk, const float* __restrict__ bk,
    const float* __restrict__ Wv, const float* __restrict__ bv,
    ushort* __restrict__ q, ushort* __restrict__ k, ushort* __restrict__ v) {
  const int lane = threadIdx.x & 63;
  const int wid  = threadIdx.x >> 6;
  const int r  = lane & 15;
  const int kg = lane >> 4;
  const float* Ws[3] = {Wq, Wk, Wv};
  const float* bs[3] = {bq, bk, bv};
  ushort* os[3] = {q, k, v};

  bf16x8 afrag[3][4][2];
  float  bias[3][4][4];
#pragma unroll
  for (int m = 0; m < 3; ++m)
#pragma unroll
    for (int nt = 0; nt < 4; ++nt) {
#pragma unroll
      for (int kk = 0; kk < 2; ++kk)
#pragma unroll
        for (int j = 0; j < 8; ++j)
          afrag[m][nt][kk][j] = (__bf16)Ws[m][(kk * 32 + kg * 8 + j) * 64 + nt * 16 + r];
#pragma unroll
      for (int j = 0; j < 4; ++j) bias[m][nt][j] = bs[m][nt * 16 + kg * 4 + j];
    }

  const int ntile = N_NODES / 16;  // 3125
  const int nw = gridDim.x * 4;
  for (int t = blockIdx.x * 4 + wid; t < ntile; t += nw) {
    const int base = t * 16;
    const float4* xr = reinterpret_cast<const float4*>(x + (size_t)(base + r) * 64 + kg * 8);
    const bf16x8 xf0 = pack_bf8(xr[0], xr[1]);
    const bf16x8 xf1 = pack_bf8(xr[8], xr[9]);
#pragma unroll
    for (int m = 0; m < 3; ++m) {
#pragma unroll
      for (int nt = 0; nt < 4; ++nt) {
        f32x4 acc = {bias[m][nt][0], bias[m][nt][1], bias[m][nt][2], bias[m][nt][3]};
        acc = __builtin_amdgcn_mfma_f32_16x16x32_bf16(afrag[m][nt][0], xf0, acc, 0, 0, 0);
        acc = __builtin_amdgcn_mfma_f32_16x16x32_bf16(afrag[m][nt][1], xf1, acc, 0, 0, 0);
        ushort4 pk;
        pk.x = f2bf(acc[0]); pk.y = f2bf(acc[1]); pk.z = f2bf(acc[2]); pk.w = f2bf(acc[3]);
        *reinterpret_cast<ushort4*>(os[m] + (size_t)(base + r) * 64 + nt * 16 + kg * 4) = pk;
      }
    }
  }
}

// ---------------- CSR build ----------------
__global__ __launch_bounds__(256) void k_hist(const int* __restrict__ edst,
                                              int* __restrict__ deg) {
  const int i = blockIdx.x * 256 + threadIdx.x;
  if (i < N_EDGES) atomicAdd(&deg[edst[i]], 1);
}

__global__ __launch_bounds__(256) void k_scan_a(const int* __restrict__ deg,
                                                int* __restrict__ bsum) {
  __shared__ int lds[256];
  const int i = blockIdx.x * 256 + threadIdx.x;
  lds[threadIdx.x] = (i < N_NODES) ? deg[i] : 0;
  __syncthreads();
  for (int s = 128; s > 0; s >>= 1) {
    if (threadIdx.x < s) lds[threadIdx.x] += lds[threadIdx.x + s];
    __syncthreads();
  }
  if (threadIdx.x == 0) bsum[blockIdx.x] = lds[0];
}

__global__ __launch_bounds__(256) void k_scan_b(int* __restrict__ bsum, int nb) {
  __shared__ int lds[256];
  const int t = threadIdx.x;
  const int d = (t < nb) ? bsum[t] : 0;
  lds[t] = d;
  __syncthreads();
  for (int off = 1; off < 256; off <<= 1) {
    const int val = (t >= off) ? lds[t - off] : 0;
    __syncthreads();
    lds[t] += val;
    __syncthreads();
  }
  if (t < nb) bsum[t] = lds[t] - d;  // exclusive
}

__global__ __launch_bounds__(256) void k_scan_c(const int* __restrict__ deg,
                                                const int* __restrict__ bsum,
                                                int* __restrict__ rowptr,
                                                int* __restrict__ woff) {
  __shared__ int lds[256];
  const int i = blockIdx.x * 256 + threadIdx.x;
  const int d = (i < N_NODES) ? deg[i] : 0;
  lds[threadIdx.x] = d;
  __syncthreads();
  for (int off = 1; off < 256; off <<= 1) {
    const int val = (threadIdx.x >= off) ? lds[threadIdx.x - off] : 0;
    __syncthreads();
    lds[threadIdx.x] += val;
    __syncthreads();
  }
  const int ex = bsum[blockIdx.x] + lds[threadIdx.x] - d;
  if (i < N_NODES) { rowptr[i] = ex; woff[i] = ex; }
  if (i == N_NODES - 1) rowptr[N_NODES] = ex + d;
}

__global__ __launch_bounds__(256) void k_scatter(const int* __restrict__ esrc,
                                                 const int* __restrict__ edst,
                                                 int* __restrict__ woff,
                                                 int* __restrict__ srcp,
                                                 int* __restrict__ eidp) {
  const int i = blockIdx.x * 256 + threadIdx.x;
  if (i < N_EDGES) {
    const int pos = atomicAdd(&woff[edst[i]], 1);
    srcp[pos] = esrc[i];
    eidp[pos] = i;
  }
}

// ---------------- ee GEMM via MFMA: 16 sorted positions/tile ----------------
// ee[j] = ea[eidp[j]] @ We + be, bf16, written dst-sorted (sequential).
__global__ __launch_bounds__(256) void k_ee_mfma(
    const int* __restrict__ eidp, const float* __restrict__ ea,
    const float* __restrict__ We, const float* __restrict__ be,
    ushort* __restrict__ ee) {
  const int lane = threadIdx.x & 63;
  const int wid  = threadIdx.x >> 6;
  const int r  = lane & 15;
  const int kg = lane >> 4;

  bf16x8 afrag[4];
  float  bias[4][4];
#pragma unroll
  for (int nt = 0; nt < 4; ++nt) {
#pragma unroll
    for (int j = 0; j < 8; ++j)
      afrag[nt][j] = (__bf16)We[(kg * 8 + j) * 64 + nt * 16 + r];
#pragma unroll
    for (int j = 0; j < 4; ++j) bias[nt][j] = be[nt * 16 + kg * 4 + j];
  }

  const int ntile = N_EDGES / 16;  // 50000
  const int nw = gridDim.x * 4;
  for (int t = blockIdx.x * 4 + wid; t < ntile; t += nw) {
    const int base = t * 16;
    const int eid = eidp[base + r];
    const float4* ar = reinterpret_cast<const float4*>(ea + (size_t)eid * 32 + kg * 8);
    const bf16x8 bfrag = pack_bf8(ar[0], ar[1]);
#pragma unroll
    for (int nt = 0; nt < 4; ++nt) {
      f32x4 acc = {bias[nt][0], bias[nt][1], bias[nt][2], bias[nt][3]};
      acc = __builtin_amdgcn_mfma_f32_16x16x32_bf16(afrag[nt], bfrag, acc, 0, 0, 0);
      ushort4 pk;
      pk.x = f2bf(acc[0]); pk.y = f2bf(acc[1]); pk.z = f2bf(acc[2]); pk.w = f2bf(acc[3]);
      *reinterpret_cast<ushort4*>(ee + (size_t)(base + r) * 64 + nt * 16 + kg * 4) = pk;
    }
  }
}

// ---------------- gather: wave per node, lane=(edge-slot, head), streaming ee ----------------
__global__ __launch_bounds__(256) void k_gather(
    const int* __restrict__ rowptr, const int* __restrict__ srcp,
    const ushort* __restrict__ ee,
    const ushort* __restrict__ qb, const ushort* __restrict__ kb,
    const ushort* __restrict__ vb, const float* __restrict__ be,
    ushort* __restrict__ osum, float* __restrict__ cnt, float* __restrict__ S) {
  const int lane = threadIdx.x & 63;
  const int wid  = threadIdx.x >> 6;
  const int h = lane & 7, ei = lane >> 3;
  float bes[8];
#pragma unroll
  for (int i = 0; i < 8; ++i) bes[i] = be[h * 8 + i];
  float sacc = 0.f;
  const int nw = gridDim.x * 4;
  for (int n = blockIdx.x * 4 + wid; n < N_NODES; n += nw) {
    const int beg = rowptr[n], end = rowptr[n + 1];
    float qv[8];
    unpack8(*reinterpret_cast<const uint4*>(qb + (size_t)n * 64 + h * 8), qv);
    float macc[8];
#pragma unroll
    for (int i = 0; i < 8; ++i) macc[i] = 0.f;
    if (ei == 0) {  // self loop: ea=0 -> ee=be
      float kv[8], vv[8];
      unpack8(*reinterpret_cast<const uint4*>(kb + (size_t)n * 64 + h * 8), kv);
      unpack8(*reinterpret_cast<const uint4*>(vb + (size_t)n * 64 + h * 8), vv);
      float sc = 0.f;
#pragma unroll
      for (int i = 0; i < 8; ++i) sc = fmaf(qv[i], kv[i] + bes[i], sc);
      const float w = __expf(sc * 0.3535533905932738f);
      sacc += w;
#pragma unroll
      for (int i = 0; i < 8; ++i) macc[i] = w * (vv[i] + bes[i]);
    }
    int p = beg + ei;
    int src = (p < end) ? srcp[p] : 0;
    for (; p < end; p += 8) {
      const int nsrc = (p + 8 < end) ? srcp[p + 8] : 0;
      float ev[8], kv[8], vv[8];
      unpack8(*reinterpret_cast<const uint4*>(ee + (size_t)p * 64 + h * 8), ev);
      unpack8(*reinterpret_cast<const uint4*>(kb + (size_t)src * 64 + h * 8), kv);
      unpack8(*reinterpret_cast<const uint4*>(vb + (size_t)src * 64 + h * 8), vv);
      float sc = 0.f;
#pragma unroll
      for (int i = 0; i < 8; ++i) sc = fmaf(qv[i], kv[i] + ev[i], sc);
      const float w = __expf(sc * 0.3535533905932738f);
      sacc += w;
#pragma unroll
      for (int i = 0; i < 8; ++i) macc[i] = fmaf(w, vv[i] + ev[i], macc[i]);
      src = nsrc;
    }
#pragma unroll
    for (int i = 0; i < 8; ++i) {
      macc[i] += __shfl_xor(macc[i], 8);
      macc[i] += __shfl_xor(macc[i], 16);
      macc[i] += __shfl_xor(macc[i], 32);
    }
    if (ei == 0) {
      uint pk[4];
#pragma unroll
      for (int i = 0; i < 4; ++i)
        pk[i] = (uint)f2bf(macc[2 * i]) | ((uint)f2bf(macc[2 * i + 1]) << 16);
      *reinterpret_cast<uint4*>(osum + (size_t)n * 64 + h * 8) =
          make_uint4(pk[0], pk[1], pk[2], pk[3]);
      if (lane == 0) cnt[n] = (float)(end - beg + 1);
    }
  }
  sacc += __shfl_xor(sacc, 8);
  sacc += __shfl_xor(sacc, 16);
  sacc += __shfl_xor(sacc, 32);
  if (ei == 0) atomicAdd(&S[h], sacc);
}

// ---------------- LN1: (osum scaled) @ Wo + bo, +x, LN -> h ----------------
__global__ __launch_bounds__(256) void k_ln1_rl(
    const ushort* __restrict__ osum, const float* __restrict__ cnt,
    const float* __restrict__ S, const float* __restrict__ x,
    const float* __restrict__ Wo, const float* __restrict__ bo,
    const float* __restrict__ g1, const float* __restrict__ b1,
    float* __restrict__ h) {
  const int lane = threadIdx.x & 63;
  const int wid  = threadIdx.x >> 6;
  float wcol[64];
#pragma unroll
  for (int j = 0; j < 64; ++j) wcol[j] = Wo[j * 64 + lane];
  const float bl = bo[lane];
  const float gl = g1[lane], b1l = b1[lane];
  const float invS = 1.0f / S[lane >> 3];
  const int nw = gridDim.x * 4;
  for (int n = blockIdx.x * 4 + wid; n < N_NODES; n += nw) {
    const float invc = 1.0f / cnt[n];
    const float val =
        __uint_as_float(((uint)osum[(size_t)n * 64 + lane]) << 16) * invS * invc;
    float acc = bl;
#pragma unroll
    for (int j = 0; j < 64; ++j) acc = fmaf(rlane(val, j), wcol[j], acc);
    const float t = x[(size_t)n * 64 + lane] + acc;
    float s = t;
    s += __shfl_xor(s, 1);  s += __shfl_xor(s, 2);  s += __shfl_xor(s, 4);
    s += __shfl_xor(s, 8);  s += __shfl_xor(s, 16); s += __shfl_xor(s, 32);
    const float m = s * (1.0f / 64.0f);
    const float d = t - m;
    float vs = d * d;
    vs += __shfl_xor(vs, 1);  vs += __shfl_xor(vs, 2);  vs += __shfl_xor(vs, 4);
    vs += __shfl_xor(vs, 8);  vs += __shfl_xor(vs, 16); vs += __shfl_xor(vs, 32);
    const float r = rsqrtf(vs * (1.0f / 64.0f) + 1e-5f);
    h[(size_t)n * 64 + lane] = d * r * gl + b1l;
  }
}

// ---------------- FFN1: f1 = gelu(h @ Wf1 + bf1), feature-half per blockIdx.y ----------------
__global__ __launch_bounds__(256) void k_ffn1_rl(
    const float* __restrict__ h, const float* __restrict__ Wf1,
    const float* __restrict__ bf1, float* __restrict__ f1) {
  const int lane = threadIdx.x & 63;
  const int wid  = threadIdx.x >> 6;
  const int f = blockIdx.y * 64 + lane;
  float wcol[64];
#pragma unroll
  for (int j = 0; j < 64; ++j) wcol[j] = Wf1[j * 128 + f];
  const float bl = bf1[f];
  const int nw = gridDim.x * 4;
  for (int n = blockIdx.x * 4 + wid; n < N_NODES; n += nw) {
    const float hr = h[(size_t)n * 64 + lane];
    float acc = bl;
#pragma unroll
    for (int j = 0; j < 64; ++j) acc = fmaf(rlane(hr, j), wcol[j], acc);
    f1[(size_t)n * 128 + f] = 0.5f * acc * (1.0f + erff(acc * 0.7071067811865475f));
  }
}

// ---------------- FFN2 + residual + LN2 -> out ----------------
__global__ __launch_bounds__(256) void k_ffn2_rl(
    const float* __restrict__ f1, const float* __restrict__ h,
    const float* __restrict__ Wf2, const float* __restrict__ bf2,
    const float* __restrict__ g2, const float* __restrict__ b2,
    float* __restrict__ out) {
  const int lane = threadIdx.x & 63;
  const int wid  = threadIdx.x >> 6;
  float wcol[128];
#pragma unroll
  for (int j = 0; j < 128; ++j) wcol[j] = Wf2[j * 64 + lane];
  const float bl = bf2[lane];
  const float gl = g2[lane], b2l = b2[lane];
  const int nw = gridDim.x * 4;
  for (int n = blockIdx.x * 4 + wid; n < N_NODES; n += nw) {
    const float a0 = f1[(size_t)n * 128 + lane];
    const float a1 = f1[(size_t)n * 128 + 64 + lane];
    float acc = bl;
#pragma unroll
    for (int j = 0; j < 64; ++j) acc = fmaf(rlane(a0, j), wcol[j], acc);
#pragma unroll
    for (int j = 0; j < 64; ++j) acc = fmaf(rlane(a1, j), wcol[64 + j], acc);
    const float t = h[(size_t)n * 64 + lane] + acc;
    float s = t;
    s += __shfl_xor(s, 1);  s += __shfl_xor(s, 2);  s += __shfl_xor(s, 4);
    s += __shfl_xor(s, 8);  s += __shfl_xor(s, 16); s += __shfl_xor(s, 32);
    const float m = s * (1.0f / 64.0f);
    const float d = t - m;
    float vs = d * d;
    vs += __shfl_xor(vs, 1);  vs += __shfl_xor(vs, 2);  vs += __shfl_xor(vs, 4);
    vs += __shfl_xor(vs, 8);  vs += __shfl_xor(vs, 16); vs += __shfl_xor(vs, 32);
    const float r = rsqrtf(vs * (1.0f / 64.0f) + 1e-5f);
    out[(size_t)n * 64 + lane] = d * r * gl + b2l;
  }
}

extern "C" void kernel_launch(void* const* d_in, const int* in_sizes, int n_in,
                              void* d_out, int out_size, void* d_ws, size_t ws_size,
                              hipStream_t stream) {
  const float* x    = (const float*)d_in[0];
  const int*   ei   = (const int*)d_in[1];
  const int*   esrc = ei;
  const int*   edst = ei + N_EDGES;
  const float* ea   = (const float*)d_in[2];
  const float* Wq   = (const float*)d_in[3];
  const float* bq   = (const float*)d_in[4];
  const float* Wk   = (const float*)d_in[5];
  const float* bk   = (const float*)d_in[6];
  const float* Wv   = (const float*)d_in[7];
  const float* bv   = (const float*)d_in[8];
  const float* We   = (const float*)d_in[9];
  const float* be   = (const float*)d_in[10];
  const float* Wo   = (const float*)d_in[11];
  const float* bo   = (const float*)d_in[12];
  const float* g1   = (const float*)d_in[13];
  const float* b1   = (const float*)d_in[14];
  const float* g2   = (const float*)d_in[15];
  const float* b2   = (const float*)d_in[16];
  const float* Wf1  = (const float*)d_in[17];
  const float* bf1  = (const float*)d_in[18];
  const float* Wf2  = (const float*)d_in[19];
  const float* bf2  = (const float*)d_in[20];

  float* ws    = (float*)d_ws;
  ushort* q    = (ushort*)(ws + Q_OFF);
  ushort* k    = (ushort*)(ws + K_OFF);
  ushort* v    = (ushort*)(ws + V_OFF);
  ushort* eeb  = (ushort*)(ws + EE_OFF);
  ushort* osum = (ushort*)(ws + OS_OFF);
  float* cnt   = ws + CNT_OFF;   // also deg / woff (sequential lifetimes)
  float* S     = ws + S_OFF;
  int*   rowptr = (int*)(ws + RP_OFF);
  int*   srcp   = (int*)(ws + SRCP_OFF);
  int*   eidp   = (int*)(ws + EIDP_OFF);
  int*   bsum   = (int*)(ws + BSUM_OFF);
  int*   deg    = (int*)cnt;
  int*   woff   = (int*)cnt;
  float* h     = ws + H_OFF;
  float* f1    = ws + F1_OFF;
  float* out   = (float*)d_out;

  hipMemsetAsync(deg, 0, (size_t)N_NODES * sizeof(int), stream);
  hipMemsetAsync(S, 0, 16 * sizeof(float), stream);

  const dim3 B(256);
  const int nodeBlocks = (N_NODES + 255) / 256;  // 196
  const int edgeBlocks = (N_EDGES + 255) / 256;  // 3125

  k_qkv_mfma<<<dim3(128), B, 0, stream>>>(x, Wq, bq, Wk, bk, Wv, bv, q, k, v);
  k_hist<<<dim3(edgeBlocks), B, 0, stream>>>(edst, deg);
  k_scan_a<<<dim3(nodeBlocks), B, 0, stream>>>(deg, bsum);
  k_scan_b<<<dim3(1), B, 0, stream>>>(bsum, nodeBlocks);
  k_scan_c<<<dim3(nodeBlocks), B, 0, stream>>>(deg, bsum, rowptr, woff);
  k_scatter<<<dim3(edgeBlocks), B, 0, stream>>>(esrc, edst, woff, srcp, eidp);
  k_ee_mfma<<<dim3(1024), B, 0, stream>>>(eidp, ea, We, be, eeb);
  k_gather<<<dim3(1024), B, 0, stream>>>(rowptr, srcp, eeb, q, k, v, be, osum, cnt, S);
  k_ln1_rl<<<dim3(256), B, 0, stream>>>(osum, cnt, S, x, Wo, bo, g1, b1, h);
  k_ffn1_rl<<<dim3(256, 2), B, 0, stream>>>(h, Wf1, bf1, f1);
  k_ffn2_rl<<<dim3(256), B, 0, stream>>>(f1, h, Wf2, bf2, g2, b2, out);
}